// Round 5
// baseline (298083.252 us; speedup 1.0000x reference)
//
#include <hip/hip_runtime.h>

// ---- problem constants ----
#define NT 365
#define NB 512          // ngrid == hidden
#define NX4 16
#define SPIN_CAP (1 << 20)   // deadlock escape: ~28ms per spin, terminates instead of wedging

typedef __attribute__((ext_vector_type(8))) short bf16x8;
typedef __attribute__((ext_vector_type(4))) float f32x4;
typedef __attribute__((ext_vector_type(4))) unsigned int u32x4;
typedef unsigned short u16;
typedef unsigned int u32;

// ---- workspace layout (bytes) ----
static constexpr size_t WB_OFF  = 0;                                   // 4 x [2048][512] bf16
static constexpr size_t B0_OFF  = WB_OFF + 4ull * 2048 * 512 * 2;      // 2048 f32
static constexpr size_t B1_OFF  = B0_OFF + 2048 * 4;
static constexpr size_t X0_OFF  = B1_OFF + 2048 * 4;                   // [512][512] bf16
static constexpr size_t HT_OFF  = X0_OFF + 512 * 512 * 2;
static constexpr size_t HT0_OFF = HT_OFF + 512 * 512 * 2;
static constexpr size_t G0_OFF  = HT0_OFF + 512 * 512 * 2;             // 4 x [512][512] bf16
static constexpr size_t G1_OFF  = G0_OFF + 4ull * 512 * 512 * 2;       // 4 x [512][512] bf16
static constexpr size_t VS_OFF  = G1_OFF + 4ull * 512 * 512 * 2;       // [8][512] f32 var partials
static constexpr size_t BAR_OFF = (VS_OFF + 8 * 512 * 4 + 255) & ~255ull;
// BAR ints: [0..511] row barriers (r*32: arrive, +16: release)
//           [512..1023] p2f flags (r*32)
//           [1024] p3cnt | [1088..1687] full-grid barrier (prologue only)
#define NBAR_INTS 1688

__device__ __forceinline__ u16 f2bf(float f) {
  u32 u = __builtin_bit_cast(u32, f);
  return (u16)((u + 0x7fffu + ((u >> 16) & 1u)) >> 16);
}
__device__ __forceinline__ float bf2f(u16 h) {
  u32 u = ((u32)h) << 16;
  return __builtin_bit_cast(float, u);
}
__device__ __forceinline__ float sigf(float x) { return 1.0f / (1.0f + __expf(-x)); }
__device__ __forceinline__ float tanha(float x) { return 1.0f - 2.0f / (__expf(2.0f * x) + 1.0f); }

// full grid barrier (prologue only), 256 wgs = 16 groups of 16
__device__ __forceinline__ void gbar(int* bar, int gen) {
  __threadfence();
  __syncthreads();
  if (threadIdx.x == 0) {
    int grp = (int)blockIdx.x >> 4;
    int old = __hip_atomic_fetch_add(bar + grp * 32, 1, __ATOMIC_ACQ_REL, __HIP_MEMORY_SCOPE_AGENT);
    if ((old & 15) == 15) {
      int rold = __hip_atomic_fetch_add(bar + 512, 1, __ATOMIC_ACQ_REL, __HIP_MEMORY_SCOPE_AGENT);
      if ((rold & 15) == 15)
        __hip_atomic_store(bar + 544, gen + 1, __ATOMIC_RELEASE, __HIP_MEMORY_SCOPE_AGENT);
    }
    for (int k = 0; k < SPIN_CAP; ++k) {
      if (__hip_atomic_load(bar + 544, __ATOMIC_ACQUIRE, __HIP_MEMORY_SCOPE_AGENT) >= gen + 1) break;
      __builtin_amdgcn_s_sleep(1);
    }
  }
  __syncthreads();
  __threadfence();
}

// 16-wg row-group barrier; releaser optionally publishes pubval to pub.
__device__ __forceinline__ void rowbar(int* rb, int r, int gen, int* pub, int pubval) {
  __threadfence();
  __syncthreads();
  if (threadIdx.x == 0) {
    int old = __hip_atomic_fetch_add(rb + r * 32, 1, __ATOMIC_ACQ_REL, __HIP_MEMORY_SCOPE_AGENT);
    if ((old & 15) == 15) {
      if (pub) __hip_atomic_store(pub, pubval, __ATOMIC_RELEASE, __HIP_MEMORY_SCOPE_AGENT);
      __hip_atomic_store(rb + r * 32 + 16, gen + 1, __ATOMIC_RELEASE, __HIP_MEMORY_SCOPE_AGENT);
    } else {
      for (int k = 0; k < SPIN_CAP; ++k) {
        if (__hip_atomic_load(rb + r * 32 + 16, __ATOMIC_ACQUIRE, __HIP_MEMORY_SCOPE_AGENT) >= gen + 1) break;
        __builtin_amdgcn_s_sleep(1);
      }
    }
  }
  __syncthreads();
  __threadfence();
}

__device__ __forceinline__ void waitflag(int* addr, int val) {
  __syncthreads();
  if (threadIdx.x == 0) {
    for (int k = 0; k < SPIN_CAP; ++k) {
      if (__hip_atomic_load(addr, __ATOMIC_ACQUIRE, __HIP_MEMORY_SCOPE_AGENT) >= val) break;
      __builtin_amdgcn_s_sleep(1);
    }
  }
  __syncthreads();
  __threadfence();
}

__global__ void init_k(float* __restrict__ out, const float* __restrict__ bout,
                       char* __restrict__ ws) {
  float* vsb = (float*)(ws + VS_OFF);
  int* bar = (int*)(ws + BAR_OFF);
  int i = blockIdx.x * 256 + threadIdx.x;
  float bo = bout[0];
  for (int j = i; j < NT * NB; j += 256 * 256) out[j] = bo;
  if (i < 8 * 512) vsb[i] = 0.0f;
  if (i < NBAR_INTS) bar[i] = 0;
  if (i == 0) out[NT * NB] = 0.0f;
}

__global__ __launch_bounds__(1024, 4) void lstm_main(
    const float* __restrict__ xg, const float* __restrict__ Win, const float* __restrict__ bin,
    const float* __restrict__ Wih0, const float* __restrict__ bih0,
    const float* __restrict__ Whh0, const float* __restrict__ bhh0,
    const float* __restrict__ Wih1, const float* __restrict__ bih1,
    const float* __restrict__ Whh1, const float* __restrict__ bhh1,
    const float* __restrict__ Wout, float* __restrict__ out, char* __restrict__ ws) {
  __shared__ __align__(16) char lraw[65536];
  u16* gFu = (u16*)lraw;               // [4][32][40] bf16 (aliased over staging)
  float* sv = (float*)(lraw + 32768);  // [16][2] f32 var partials (aliased)
  u16* wb = (u16*)(ws + WB_OFF);
  float* b0 = (float*)(ws + B0_OFF);
  float* b1 = (float*)(ws + B1_OFF);
  u16* x0b = (u16*)(ws + X0_OFF);
  u16* htb = (u16*)(ws + HT_OFF);
  u16* ht0b = (u16*)(ws + HT0_OFF);
  u16* g0b = (u16*)(ws + G0_OFF);
  u16* g1b = (u16*)(ws + G1_OFF);
  float* vsb = (float*)(ws + VS_OFF);
  int* bar = (int*)(ws + BAR_OFF);
  int* rbars = bar;
  int* p2f = bar + 512;
  int* p3cnt = bar + 1024;
  int* gb = bar + 1088;

  const int tid = threadIdx.x;
  const int gid = blockIdx.x;
  const int gtid = gid * 1024 + tid;
  const int r = gid >> 4, c = gid & 15;   // same-c wgs share a weight slice per XCD
  const int rbase = r * 32, cbase = c * 32;
  const int w = tid >> 6, lane = tid & 63, l15 = lane & 15, kg = lane >> 4;
  const int g = w >> 2, m = (w >> 1) & 1, n = w & 1;  // wave's fragment: gate g, m/n halves
  const int urow = tid >> 5, ucol = tid & 31;          // update-phase element
  const int ub = rbase + urow, uh = cbase + ucol;

  // loop-invariant per-thread preloads
  float winr[16];
  #pragma unroll
  for (int j = 0; j < 16; ++j) winr[j] = Win[(size_t)uh * NX4 + j];
  const float binr = bin[uh];
  const float woutr = Wout[uh];

  // ================= prologue =================
  {
    const float* srcs[4] = {Wih0, Whh0, Wih1, Whh1};
    #pragma unroll
    for (int mm = 0; mm < 4; ++mm) {
      const float4* s4 = (const float4*)srcs[mm];
      ushort4* d4 = (ushort4*)(wb + (size_t)mm * 2048 * 512);
      float4 v = s4[gtid];
      ushort4 o;
      o.x = f2bf(v.x); o.y = f2bf(v.y); o.z = f2bf(v.z); o.w = f2bf(v.w);
      d4[gtid] = o;
    }
    if (gtid < 2048) { b0[gtid] = bih0[gtid] + bhh0[gtid]; b1[gtid] = bih1[gtid] + bhh1[gtid]; }
    if (gtid < 512 * 512 / 2) ((u32*)htb)[gtid] = 0u;
    {
      const float* xr = xg + (size_t)ub * NX4;
      float a = binr;
      #pragma unroll
      for (int j = 0; j < 16; ++j) a += winr[j] * xr[j];
      x0b[(size_t)ub * 512 + uh] = f2bf(fmaxf(a, 0.0f));
    }
  }
  gbar(gb, 0);

  const float bias0l = b0[g * 512 + cbase + n * 16 + l15];
  const float bias1l = b1[g * 512 + cbase + n * 16 + l15];
  const int arow = m * 16 + l15;
  const int abase = arow << 11;
  const int axor = (arow & 7) << 4;
  const u16* Wl0 = wb + (size_t)(g * 512 + cbase + n * 16 + l15) * 512;
  float ctreg = 0.0f;  // this thread's cell-state element — register-resident
  int rgen = 0;        // row-barrier generation

  // ================= time loop =================
  for (int t = 0; t < NT; ++t) {
    // ---- P1: layer-0 gates + cell update ----
    #pragma unroll
    for (int p = 0; p < 4; ++p) {   // stage [x0 | ht] rows rbase..+32 (64KB, swizzled)
      int ch = p * 1024 + tid;
      int row = ch >> 7, cc = ch & 127;
      const u16* sp = (cc < 64) ? x0b + (size_t)(rbase + row) * 512 + cc * 8
                                : htb + (size_t)(rbase + row) * 512 + (cc - 64) * 8;
      u32x4 v = __builtin_nontemporal_load((const u32x4*)sp);
      *(u32x4*)&lraw[(row << 11) | ((cc << 4) ^ ((row & 7) << 4))] = v;
    }
    __syncthreads();
    {
      f32x4 acc = {0.f, 0.f, 0.f, 0.f};
      const u16* W0 = Wl0;                       // Wih0 row
      const u16* W1 = Wl0 + 2048ull * 512;       // Whh0 row
      #pragma unroll 4
      for (int ks = 0; ks < 16; ++ks) {
        int kk = ks * 32 + kg * 8;
        bf16x8 a = *(const bf16x8*)&lraw[abase | (((kk >> 3) << 4) ^ axor)];
        bf16x8 q = *(const bf16x8*)(W0 + kk);
        acc = __builtin_amdgcn_mfma_f32_16x16x32_bf16(a, q, acc, 0, 0, 0);
      }
      #pragma unroll 4
      for (int ks = 0; ks < 16; ++ks) {
        int kk = ks * 32 + kg * 8;
        bf16x8 a = *(const bf16x8*)&lraw[abase | (((64 + (kk >> 3)) << 4) ^ axor)];
        bf16x8 q = *(const bf16x8*)(W1 + kk);
        acc = __builtin_amdgcn_mfma_f32_16x16x32_bf16(a, q, acc, 0, 0, 0);
      }
      __syncthreads();  // staging dead; reuse LDS as gFu
      #pragma unroll
      for (int q = 0; q < 4; ++q) {
        float v = acc[q] + bias0l;
        float a = (g == 2) ? tanha(v) : sigf(v);
        gFu[g * 1280 + (m * 16 + kg * 4 + q) * 40 + n * 16 + l15] = f2bf(a);
      }
    }
    __syncthreads();
    {
      u16 gi = gFu[0 * 1280 + urow * 40 + ucol];
      u16 gf = gFu[1 * 1280 + urow * 40 + ucol];
      u16 gc = gFu[2 * 1280 + urow * 40 + ucol];
      u16 go = gFu[3 * 1280 + urow * 40 + ucol];
      float i0 = bf2f(gi), f0 = bf2f(gf), c0 = bf2f(gc), o0 = bf2f(go);
      ctreg = f0 * ctreg + i0 * c0;
      float h0v = o0 * tanha(ctreg);
      size_t eo = (size_t)ub * 512 + uh;
      __builtin_nontemporal_store(f2bf(h0v), ht0b + eo);
      __builtin_nontemporal_store(gi, g0b + 0 * 262144 + eo);
      __builtin_nontemporal_store(gf, g0b + 1 * 262144 + eo);
      __builtin_nontemporal_store(gc, g0b + 2 * 262144 + eo);
      __builtin_nontemporal_store(go, g0b + 3 * 262144 + eo);
    }
    rowbar(rbars, r, rgen, nullptr, 0); ++rgen;

    // ---- P2: layer-1 raw gates ----
    #pragma unroll
    for (int p = 0; p < 4; ++p) {   // stage [x0 | ht0]
      int ch = p * 1024 + tid;
      int row = ch >> 7, cc = ch & 127;
      const u16* sp = (cc < 64) ? x0b + (size_t)(rbase + row) * 512 + cc * 8
                                : ht0b + (size_t)(rbase + row) * 512 + (cc - 64) * 8;
      u32x4 v = __builtin_nontemporal_load((const u32x4*)sp);
      *(u32x4*)&lraw[(row << 11) | ((cc << 4) ^ ((row & 7) << 4))] = v;
    }
    __syncthreads();
    {
      f32x4 acc = {0.f, 0.f, 0.f, 0.f};
      const u16* W0 = Wl0 + 2ull * 2048 * 512;   // Wih1
      const u16* W1 = Wl0 + 3ull * 2048 * 512;   // Whh1
      #pragma unroll 4
      for (int ks = 0; ks < 16; ++ks) {
        int kk = ks * 32 + kg * 8;
        bf16x8 a = *(const bf16x8*)&lraw[abase | (((kk >> 3) << 4) ^ axor)];
        bf16x8 q = *(const bf16x8*)(W0 + kk);
        acc = __builtin_amdgcn_mfma_f32_16x16x32_bf16(a, q, acc, 0, 0, 0);
      }
      #pragma unroll 4
      for (int ks = 0; ks < 16; ++ks) {
        int kk = ks * 32 + kg * 8;
        bf16x8 a = *(const bf16x8*)&lraw[abase | (((64 + (kk >> 3)) << 4) ^ axor)];
        bf16x8 q = *(const bf16x8*)(W1 + kk);
        acc = __builtin_amdgcn_mfma_f32_16x16x32_bf16(a, q, acc, 0, 0, 0);
      }
      // g1b rows rbase are still being read by other groups' P3(t-1): gate on p3cnt
      if (t > 0) waitflag(p3cnt, 16 * t);
      #pragma unroll
      for (int q = 0; q < 4; ++q) {
        int b_ = rbase + m * 16 + kg * 4 + q;
        __builtin_nontemporal_store(f2bf(acc[q] + bias1l),
            g1b + (size_t)g * 262144 + (size_t)b_ * 512 + cbase + n * 16 + l15);
      }
    }
    rowbar(rbars, r, rgen, p2f + r * 32, t + 1); ++rgen;

    // ---- P3: [B,B] score matmuls + layer-1 update + outputs ----
    waitflag(p2f + c * 32, t + 1);   // group c's P2(t) done
    {
      f32x4 acc = {0.f, 0.f, 0.f, 0.f};
      const u16* As = g0b + (size_t)g * 262144 + (size_t)(rbase + m * 16 + l15) * 512;
      const u16* Bs = g1b + (size_t)g * 262144 + (size_t)(cbase + n * 16 + l15) * 512;
      #pragma unroll 4
      for (int ks = 0; ks < 16; ++ks) {
        int kk = ks * 32 + kg * 8;
        bf16x8 a = __builtin_nontemporal_load((const bf16x8*)(As + kk));
        bf16x8 q = __builtin_nontemporal_load((const bf16x8*)(Bs + kk));
        acc = __builtin_amdgcn_mfma_f32_16x16x32_bf16(a, q, acc, 0, 0, 0);
      }
      float s1 = acc[0] + acc[1] + acc[2] + acc[3];
      float s2 = acc[0] * acc[0] + acc[1] * acc[1] + acc[2] * acc[2] + acc[3] * acc[3];
      #pragma unroll
      for (int off = 32; off > 0; off >>= 1) { s1 += __shfl_xor(s1, off); s2 += __shfl_xor(s2, off); }
      if (lane == 0) { sv[w * 2] = s1; sv[w * 2 + 1] = s2; }
      #pragma unroll
      for (int q = 0; q < 4; ++q)
        gFu[g * 1280 + (m * 16 + kg * 4 + q) * 40 + n * 16 + l15] = f2bf(acc[q]);
    }
    __syncthreads();
    {
      float i1 = sigf(bf2f(gFu[0 * 1280 + urow * 40 + ucol]));
      float f1 = sigf(bf2f(gFu[1 * 1280 + urow * 40 + ucol]));
      float c1 = tanha(bf2f(gFu[2 * 1280 + urow * 40 + ucol]));
      float o1 = sigf(bf2f(gFu[3 * 1280 + urow * 40 + ucol]));
      ctreg = f1 * ctreg + i1 * c1;
      float hv = o1 * tanha(ctreg);
      __builtin_nontemporal_store(f2bf(hv), htb + (size_t)ub * 512 + uh);
      float op = hv * woutr;
      op += __shfl_down(op, 16, 32);
      op += __shfl_down(op, 8, 32);
      op += __shfl_down(op, 4, 32);
      op += __shfl_down(op, 2, 32);
      op += __shfl_down(op, 1, 32);
      if ((tid & 31) == 0) atomicAdd(out + (size_t)t * NB + ub, op);
      if (tid < 8) {
        int gg = tid >> 1, part = tid & 1;
        float val = sv[(gg * 4 + 0) * 2 + part] + sv[(gg * 4 + 1) * 2 + part] +
                    sv[(gg * 4 + 2) * 2 + part] + sv[(gg * 4 + 3) * 2 + part];
        atomicAdd(vsb + (size_t)(gg * 2 + part) * 512 + t, val);
      }
      if (t + 1 < NT) {
        const float* xr = xg + ((size_t)(t + 1) * NB + ub) * NX4;
        float a = binr;
        #pragma unroll
        for (int j = 0; j < 16; ++j) a += winr[j] * xr[j];
        __builtin_nontemporal_store(f2bf(fmaxf(a, 0.0f)), x0b + (size_t)ub * 512 + uh);
      }
    }
    rowbar(rbars, r, rgen, nullptr, 0); ++rgen;
    if (tid == 0 && c == 0)
      __hip_atomic_fetch_add(p3cnt, 1, __ATOMIC_ACQ_REL, __HIP_MEMORY_SCOPE_AGENT);
  }

  // ================= epilogue: norm =================
  waitflag(p3cnt, 16 * NT);
  if (gid == 0) {
    float s = 0.0f;
    const float invN = 1.0f / 262144.0f;
    for (int i = tid; i < 4 * NT; i += 1024) {
      int gg = i / NT, tt = i - gg * NT;
      float sum = vsb[(size_t)(gg * 2) * 512 + tt];
      float sq = vsb[(size_t)(gg * 2 + 1) * 512 + tt];
      float mean = sum * invN;
      s += (sq * invN - mean * mean) * 0.25f;
    }
    #pragma unroll
    for (int off = 32; off > 0; off >>= 1) s += __shfl_xor(s, off);
    float* red = (float*)lraw;
    __syncthreads();
    if (lane == 0) red[w] = s;
    __syncthreads();
    if (tid == 0) {
      float tot = 0.0f;
      #pragma unroll
      for (int j = 0; j < 16; ++j) tot += red[j];
      out[NT * NB] = tot / (float)NT;
    }
  }
}

extern "C" void kernel_launch(void* const* d_in, const int* in_sizes, int n_in,
                              void* d_out, int out_size, void* d_ws, size_t ws_size,
                              hipStream_t stream) {
  const float* xg = (const float*)d_in[0];
  const float* Win = (const float*)d_in[1];
  const float* bin = (const float*)d_in[2];
  const float* Wih0 = (const float*)d_in[3];
  const float* bih0 = (const float*)d_in[4];
  const float* Whh0 = (const float*)d_in[5];
  const float* bhh0 = (const float*)d_in[6];
  const float* Wih1 = (const float*)d_in[7];
  const float* bih1 = (const float*)d_in[8];
  const float* Whh1 = (const float*)d_in[9];
  const float* bhh1 = (const float*)d_in[10];
  const float* Wout = (const float*)d_in[11];
  const float* bout = (const float*)d_in[12];
  float* out = (float*)d_out;
  char* ws = (char*)d_ws;

  hipLaunchKernelGGL(init_k, dim3(256), dim3(256), 0, stream, out, bout, ws);

  void* args[] = {(void*)&xg, (void*)&Win, (void*)&bin, (void*)&Wih0, (void*)&bih0,
                  (void*)&Whh0, (void*)&bhh0, (void*)&Wih1, (void*)&bih1,
                  (void*)&Whh1, (void*)&bhh1, (void*)&Wout, (void*)&out, (void*)&ws};
  hipLaunchCooperativeKernel((void*)lstm_main, dim3(256), dim3(1024), args, 0, stream);
}

// Round 7
// 40189.584 us; speedup vs baseline: 7.4169x; 7.4169x over previous
//
#include <hip/hip_runtime.h>

// ---- problem constants ----
#define NT 365
#define NB 512          // ngrid == hidden
#define NX4 16
#define SPIN_CAP (1 << 20)   // escape hatch: terminate instead of wedging on sync bug

typedef __attribute__((ext_vector_type(8))) short bf16x8;
typedef __attribute__((ext_vector_type(4))) float f32x4;
typedef __attribute__((ext_vector_type(4))) unsigned int u32x4;
typedef unsigned short u16;
typedef unsigned int u32;

// ---- workspace layout (bytes) ----
static constexpr size_t WB_OFF  = 0;                                   // 4 x [2048][512] bf16
static constexpr size_t B0_OFF  = WB_OFF + 4ull * 2048 * 512 * 2;      // 2048 f32
static constexpr size_t B1_OFF  = B0_OFF + 2048 * 4;
static constexpr size_t X0_OFF  = B1_OFF + 2048 * 4;                   // [512][512] bf16
static constexpr size_t HT_OFF  = X0_OFF + 512 * 512 * 2;
static constexpr size_t HT0_OFF = HT_OFF + 512 * 512 * 2;
static constexpr size_t G0_OFF  = HT0_OFF + 512 * 512 * 2;             // 4 x [512][512] bf16
static constexpr size_t G1_OFF  = G0_OFF + 4ull * 512 * 512 * 2;       // 4 x [512][512] bf16
static constexpr size_t VS_OFF  = G1_OFF + 4ull * 512 * 512 * 2;       // [8][512] f32 var partials
static constexpr size_t BAR_OFF = (VS_OFF + 8 * 512 * 4 + 255) & ~255ull; // 600 ints
#define NBAR_INTS 600

__device__ __forceinline__ u16 f2bf(float f) {
  u32 u = __builtin_bit_cast(u32, f);
  return (u16)((u + 0x7fffu + ((u >> 16) & 1u)) >> 16);
}
__device__ __forceinline__ float bf2f(u16 h) {
  u32 u = ((u32)h) << 16;
  return __builtin_bit_cast(float, u);
}
__device__ __forceinline__ float sigf(float x) { return 1.0f / (1.0f + __expf(-x)); }
__device__ __forceinline__ float tanha(float x) { return 1.0f - 2.0f / (__expf(2.0f * x) + 1.0f); }

// 2-level grid barrier, monotonic counters (R1-proven). Requires grid == 256.
__device__ __forceinline__ void gbar(int* bar, int gen) {
  __syncthreads();
  if (threadIdx.x == 0) {
    __threadfence();
    int grp = (int)blockIdx.x >> 4;
    int old = __hip_atomic_fetch_add(bar + grp * 32, 1, __ATOMIC_RELAXED, __HIP_MEMORY_SCOPE_AGENT);
    if ((old & 15) == 15) {
      int rold = __hip_atomic_fetch_add(bar + 512, 1, __ATOMIC_RELAXED, __HIP_MEMORY_SCOPE_AGENT);
      if ((rold & 15) == 15)
        __hip_atomic_store(bar + 544, gen + 1, __ATOMIC_RELEASE, __HIP_MEMORY_SCOPE_AGENT);
    }
    for (int k = 0; k < SPIN_CAP; ++k) {
      if (__hip_atomic_load(bar + 544, __ATOMIC_RELAXED, __HIP_MEMORY_SCOPE_AGENT) >= gen + 1) break;
      __builtin_amdgcn_s_sleep(1);
    }
    __threadfence();
  }
  __syncthreads();
}

__global__ void init_k(float* __restrict__ out, const float* __restrict__ bout,
                       char* __restrict__ ws) {
  float* vsb = (float*)(ws + VS_OFF);
  int* bar = (int*)(ws + BAR_OFF);
  int i = blockIdx.x * 256 + threadIdx.x;
  float bo = bout[0];
  for (int j = i; j < NT * NB; j += 256 * 256) out[j] = bo;
  if (i < 8 * 512) vsb[i] = 0.0f;
  if (i < NBAR_INTS) bar[i] = 0;
  if (i == 0) out[NT * NB] = 0.0f;
}

__global__ __launch_bounds__(1024, 4) void lstm_main(
    const float* __restrict__ xg, const float* __restrict__ Win, const float* __restrict__ bin,
    const float* __restrict__ Wih0, const float* __restrict__ bih0,
    const float* __restrict__ Whh0, const float* __restrict__ bhh0,
    const float* __restrict__ Wih1, const float* __restrict__ bih1,
    const float* __restrict__ Whh1, const float* __restrict__ bhh1,
    const float* __restrict__ Wout, float* __restrict__ out, char* __restrict__ ws) {
  __shared__ __align__(16) char lraw[65536];
  u16* gFu = (u16*)lraw;               // [4][32][40] bf16 (aliased over staging)
  float* sv = (float*)(lraw + 32768);  // [16][2] f32 var partials (aliased)
  u16* wb = (u16*)(ws + WB_OFF);
  float* b0 = (float*)(ws + B0_OFF);
  float* b1 = (float*)(ws + B1_OFF);
  u16* x0b = (u16*)(ws + X0_OFF);
  u16* htb = (u16*)(ws + HT_OFF);
  u16* ht0b = (u16*)(ws + HT0_OFF);
  u16* g0b = (u16*)(ws + G0_OFF);
  u16* g1b = (u16*)(ws + G1_OFF);
  float* vsb = (float*)(ws + VS_OFF);
  int* bar = (int*)(ws + BAR_OFF);

  const int tid = threadIdx.x;
  const int gid = blockIdx.x;
  const int gtid = gid * 1024 + tid;
  const int r = gid >> 4, c = gid & 15;   // same-c wgs land on one XCD -> weight slice L2-resident
  const int rbase = r * 32, cbase = c * 32;
  const int w = tid >> 6, lane = tid & 63, l15 = lane & 15, kg = lane >> 4;
  const int g = w >> 2, m = (w >> 1) & 1, n = w & 1;  // wave's fragment: gate g, m/n halves
  const int urow = tid >> 5, ucol = tid & 31;          // update-phase element
  const int ub = rbase + urow, uh = cbase + ucol;

  // loop-invariant per-thread preloads
  float winr[16];
  #pragma unroll
  for (int j = 0; j < 16; ++j) winr[j] = Win[(size_t)uh * NX4 + j];
  const float binr = bin[uh];
  const float woutr = Wout[uh];

  // ================= prologue =================
  {
    const float* srcs[4] = {Wih0, Whh0, Wih1, Whh1};
    #pragma unroll
    for (int mm = 0; mm < 4; ++mm) {
      const float4* s4 = (const float4*)srcs[mm];
      ushort4* d4 = (ushort4*)(wb + (size_t)mm * 2048 * 512);
      float4 v = s4[gtid];
      ushort4 o;
      o.x = f2bf(v.x); o.y = f2bf(v.y); o.z = f2bf(v.z); o.w = f2bf(v.w);
      d4[gtid] = o;
    }
    if (gtid < 2048) { b0[gtid] = bih0[gtid] + bhh0[gtid]; b1[gtid] = bih1[gtid] + bhh1[gtid]; }
    if (gtid < 512 * 512 / 2) ((u32*)htb)[gtid] = 0u;
    {
      const float* xr = xg + (size_t)ub * NX4;
      float a = binr;
      #pragma unroll
      for (int j = 0; j < 16; ++j) a += winr[j] * xr[j];
      x0b[(size_t)ub * 512 + uh] = f2bf(fmaxf(a, 0.0f));
    }
  }
  int gen = 0;
  gbar(bar, gen); ++gen;

  const float bias0l = b0[g * 512 + cbase + n * 16 + l15];
  const float bias1l = b1[g * 512 + cbase + n * 16 + l15];
  const int arow = m * 16 + l15;
  const int abase = arow << 11;
  const int axor = (arow & 7) << 4;
  const u16* Wl0 = wb + (size_t)(g * 512 + cbase + n * 16 + l15) * 512;
  float ctreg = 0.0f;  // this thread's cell-state element — register-resident
  // ================= time loop =================
  for (int t = 0; t < NT; ++t) {
    // ---- P1: layer-0 gates + cell update ----
    #pragma unroll
    for (int p = 0; p < 4; ++p) {   // stage [x0 | ht] rows rbase..+32 (64KB, swizzled)
      int ch = p * 1024 + tid;
      int row = ch >> 7, cc = ch & 127;
      const u16* sp = (cc < 64) ? x0b + (size_t)(rbase + row) * 512 + cc * 8
                                : htb + (size_t)(rbase + row) * 512 + (cc - 64) * 8;
      u32x4 v = __builtin_nontemporal_load((const u32x4*)sp);
      *(u32x4*)&lraw[(row << 11) | ((cc << 4) ^ ((row & 7) << 4))] = v;
    }
    __syncthreads();
    {
      f32x4 acc = {0.f, 0.f, 0.f, 0.f};
      const u16* W0 = Wl0;                       // Wih0 row (regular loads: keep L2-resident)
      const u16* W1 = Wl0 + 2048ull * 512;       // Whh0 row
      #pragma unroll
      for (int ks = 0; ks < 16; ++ks) {
        int kk = ks * 32 + kg * 8;
        bf16x8 a = *(const bf16x8*)&lraw[abase | (((kk >> 3) << 4) ^ axor)];
        bf16x8 q = *(const bf16x8*)(W0 + kk);
        acc = __builtin_amdgcn_mfma_f32_16x16x32_bf16(a, q, acc, 0, 0, 0);
      }
      #pragma unroll
      for (int ks = 0; ks < 16; ++ks) {
        int kk = ks * 32 + kg * 8;
        bf16x8 a = *(const bf16x8*)&lraw[abase | (((64 + (kk >> 3)) << 4) ^ axor)];
        bf16x8 q = *(const bf16x8*)(W1 + kk);
        acc = __builtin_amdgcn_mfma_f32_16x16x32_bf16(a, q, acc, 0, 0, 0);
      }
      __syncthreads();  // staging dead; reuse LDS as gFu
      #pragma unroll
      for (int q = 0; q < 4; ++q) {
        float v = acc[q] + bias0l;
        float a = (g == 2) ? tanha(v) : sigf(v);
        gFu[g * 1280 + (m * 16 + kg * 4 + q) * 40 + n * 16 + l15] = f2bf(a);
      }
    }
    __syncthreads();
    {
      u16 gi = gFu[0 * 1280 + urow * 40 + ucol];
      u16 gf = gFu[1 * 1280 + urow * 40 + ucol];
      u16 gc = gFu[2 * 1280 + urow * 40 + ucol];
      u16 go = gFu[3 * 1280 + urow * 40 + ucol];
      float i0 = bf2f(gi), f0 = bf2f(gf), c0 = bf2f(gc), o0 = bf2f(go);
      ctreg = f0 * ctreg + i0 * c0;
      float h0v = o0 * tanha(ctreg);
      size_t eo = (size_t)ub * 512 + uh;
      __builtin_nontemporal_store(f2bf(h0v), ht0b + eo);
      __builtin_nontemporal_store(gi, g0b + 0 * 262144 + eo);
      __builtin_nontemporal_store(gf, g0b + 1 * 262144 + eo);
      __builtin_nontemporal_store(gc, g0b + 2 * 262144 + eo);
      __builtin_nontemporal_store(go, g0b + 3 * 262144 + eo);
    }
    gbar(bar, gen); ++gen;

    // ---- P2: layer-1 raw gates (direct global write, no redistribution) ----
    #pragma unroll
    for (int p = 0; p < 4; ++p) {   // stage [x0 | ht0]
      int ch = p * 1024 + tid;
      int row = ch >> 7, cc = ch & 127;
      const u16* sp = (cc < 64) ? x0b + (size_t)(rbase + row) * 512 + cc * 8
                                : ht0b + (size_t)(rbase + row) * 512 + (cc - 64) * 8;
      u32x4 v = __builtin_nontemporal_load((const u32x4*)sp);
      *(u32x4*)&lraw[(row << 11) | ((cc << 4) ^ ((row & 7) << 4))] = v;
    }
    __syncthreads();
    {
      f32x4 acc = {0.f, 0.f, 0.f, 0.f};
      const u16* W0 = Wl0 + 2ull * 2048 * 512;   // Wih1
      const u16* W1 = Wl0 + 3ull * 2048 * 512;   // Whh1
      #pragma unroll
      for (int ks = 0; ks < 16; ++ks) {
        int kk = ks * 32 + kg * 8;
        bf16x8 a = *(const bf16x8*)&lraw[abase | (((kk >> 3) << 4) ^ axor)];
        bf16x8 q = *(const bf16x8*)(W0 + kk);
        acc = __builtin_amdgcn_mfma_f32_16x16x32_bf16(a, q, acc, 0, 0, 0);
      }
      #pragma unroll
      for (int ks = 0; ks < 16; ++ks) {
        int kk = ks * 32 + kg * 8;
        bf16x8 a = *(const bf16x8*)&lraw[abase | (((64 + (kk >> 3)) << 4) ^ axor)];
        bf16x8 q = *(const bf16x8*)(W1 + kk);
        acc = __builtin_amdgcn_mfma_f32_16x16x32_bf16(a, q, acc, 0, 0, 0);
      }
      #pragma unroll
      for (int q = 0; q < 4; ++q) {
        int b_ = rbase + m * 16 + kg * 4 + q;
        __builtin_nontemporal_store(f2bf(acc[q] + bias1l),
            g1b + (size_t)g * 262144 + (size_t)b_ * 512 + cbase + n * 16 + l15);
      }
    }
    gbar(bar, gen); ++gen;

    // ---- P3: [B,B] score matmuls + layer-1 update + outputs ----
    {
      f32x4 acc = {0.f, 0.f, 0.f, 0.f};
      const u16* As = g0b + (size_t)g * 262144 + (size_t)(rbase + m * 16 + l15) * 512;
      const u16* Bs = g1b + (size_t)g * 262144 + (size_t)(cbase + n * 16 + l15) * 512;
      #pragma unroll
      for (int ks = 0; ks < 16; ++ks) {
        int kk = ks * 32 + kg * 8;
        bf16x8 a = __builtin_nontemporal_load((const bf16x8*)(As + kk));
        bf16x8 q = __builtin_nontemporal_load((const bf16x8*)(Bs + kk));
        acc = __builtin_amdgcn_mfma_f32_16x16x32_bf16(a, q, acc, 0, 0, 0);
      }
      float s1 = acc[0] + acc[1] + acc[2] + acc[3];
      float s2 = acc[0] * acc[0] + acc[1] * acc[1] + acc[2] * acc[2] + acc[3] * acc[3];
      #pragma unroll
      for (int off = 32; off > 0; off >>= 1) { s1 += __shfl_xor(s1, off); s2 += __shfl_xor(s2, off); }
      if (lane == 0) { sv[w * 2] = s1; sv[w * 2 + 1] = s2; }
      #pragma unroll
      for (int q = 0; q < 4; ++q)
        gFu[g * 1280 + (m * 16 + kg * 4 + q) * 40 + n * 16 + l15] = f2bf(acc[q]);
    }
    __syncthreads();
    {
      float i1 = sigf(bf2f(gFu[0 * 1280 + urow * 40 + ucol]));
      float f1 = sigf(bf2f(gFu[1 * 1280 + urow * 40 + ucol]));
      float c1 = tanha(bf2f(gFu[2 * 1280 + urow * 40 + ucol]));
      float o1 = sigf(bf2f(gFu[3 * 1280 + urow * 40 + ucol]));
      ctreg = f1 * ctreg + i1 * c1;
      float hv = o1 * tanha(ctreg);
      __builtin_nontemporal_store(f2bf(hv), htb + (size_t)ub * 512 + uh);
      float op = hv * woutr;
      op += __shfl_down(op, 16, 32);
      op += __shfl_down(op, 8, 32);
      op += __shfl_down(op, 4, 32);
      op += __shfl_down(op, 2, 32);
      op += __shfl_down(op, 1, 32);
      if ((tid & 31) == 0) atomicAdd(out + (size_t)t * NB + ub, op);
      if (tid < 8) {
        int gg = tid >> 1, part = tid & 1;
        float val = sv[(gg * 4 + 0) * 2 + part] + sv[(gg * 4 + 1) * 2 + part] +
                    sv[(gg * 4 + 2) * 2 + part] + sv[(gg * 4 + 3) * 2 + part];
        atomicAdd(vsb + (size_t)(gg * 2 + part) * 512 + t, val);
      }
      if (t + 1 < NT) {
        const float* xr = xg + ((size_t)(t + 1) * NB + ub) * NX4;
        float a = binr;
        #pragma unroll
        for (int j = 0; j < 16; ++j) a += winr[j] * xr[j];
        __builtin_nontemporal_store(f2bf(fmaxf(a, 0.0f)), x0b + (size_t)ub * 512 + uh);
      }
    }
    gbar(bar, gen); ++gen;
  }

  // ================= epilogue: norm =================
  if (gid == 0) {
    float s = 0.0f;
    const float invN = 1.0f / 262144.0f;
    for (int i = tid; i < 4 * NT; i += 1024) {
      int gg = i / NT, tt = i - gg * NT;
      float sum = vsb[(size_t)(gg * 2) * 512 + tt];
      float sq = vsb[(size_t)(gg * 2 + 1) * 512 + tt];
      float mean = sum * invN;
      s += (sq * invN - mean * mean) * 0.25f;
    }
    #pragma unroll
    for (int off = 32; off > 0; off >>= 1) s += __shfl_xor(s, off);
    float* red = (float*)lraw;
    if (lane == 0) red[w] = s;
    __syncthreads();
    if (tid == 0) {
      float tot = 0.0f;
      #pragma unroll
      for (int j = 0; j < 16; ++j) tot += red[j];
      out[NT * NB] = tot / (float)NT;
    }
  }
}

extern "C" void kernel_launch(void* const* d_in, const int* in_sizes, int n_in,
                              void* d_out, int out_size, void* d_ws, size_t ws_size,
                              hipStream_t stream) {
  const float* xg = (const float*)d_in[0];
  const float* Win = (const float*)d_in[1];
  const float* bin = (const float*)d_in[2];
  const float* Wih0 = (const float*)d_in[3];
  const float* bih0 = (const float*)d_in[4];
  const float* Whh0 = (const float*)d_in[5];
  const float* bhh0 = (const float*)d_in[6];
  const float* Wih1 = (const float*)d_in[7];
  const float* bih1 = (const float*)d_in[8];
  const float* Whh1 = (const float*)d_in[9];
  const float* bhh1 = (const float*)d_in[10];
  const float* Wout = (const float*)d_in[11];
  const float* bout = (const float*)d_in[12];
  float* out = (float*)d_out;
  char* ws = (char*)d_ws;

  hipLaunchKernelGGL(init_k, dim3(256), dim3(256), 0, stream, out, bout, ws);

  void* args[] = {(void*)&xg, (void*)&Win, (void*)&bin, (void*)&Wih0, (void*)&bih0,
                  (void*)&Whh0, (void*)&bhh0, (void*)&Wih1, (void*)&bih1,
                  (void*)&Whh1, (void*)&bhh1, (void*)&Wout, (void*)&out, (void*)&ws};
  hipLaunchCooperativeKernel((void*)lstm_main, dim3(256), dim3(1024), args, 0, stream);
}

// Round 8
// 35356.046 us; speedup vs baseline: 8.4309x; 1.1367x over previous
//
#include <hip/hip_runtime.h>

// ---- problem constants ----
#define NT 365
#define NB 512          // ngrid == hidden
#define NX4 16
#define SPIN_CAP (1 << 20)   // escape hatch: terminate instead of wedging on sync bug

typedef __attribute__((ext_vector_type(8))) short bf16x8;
typedef __attribute__((ext_vector_type(4))) float f32x4;
typedef __attribute__((ext_vector_type(4))) unsigned int u32x4;
typedef unsigned short u16;
typedef unsigned int u32;

// ---- workspace layout (bytes) ----
static constexpr size_t WB_OFF  = 0;                                   // 4 x [2048][512] bf16
static constexpr size_t B0_OFF  = WB_OFF + 4ull * 2048 * 512 * 2;      // 2048 f32
static constexpr size_t B1_OFF  = B0_OFF + 2048 * 4;
static constexpr size_t X0_OFF  = B1_OFF + 2048 * 4;                   // [512][512] bf16
static constexpr size_t HT_OFF  = X0_OFF + 512 * 512 * 2;
static constexpr size_t HT0_OFF = HT_OFF + 512 * 512 * 2;
static constexpr size_t G0_OFF  = HT0_OFF + 512 * 512 * 2;             // 4 x [512][512] bf16
static constexpr size_t G1_OFF  = G0_OFF + 4ull * 512 * 512 * 2;       // 2 parity bufs x 2MB
static constexpr size_t VSP_OFF = G1_OFF + 2ull * 4 * 512 * 512 * 2;   // [256 wg][8 slot][368] f32
static constexpr size_t NRM_OFF = VSP_OFF + 256ull * 8 * 368 * 4;      // [368] f32
static constexpr size_t BAR_OFF = (NRM_OFF + 368 * 4 + 255) & ~255ull;
// BAR ints: [0..511] rbar arrive (r*32); [512..1023] rbar release (512+r*32)
//           [1024..] gbar: group (1024+grp*32), root 1024+512, release 1024+544
#define NBAR_INTS 1600

__device__ __forceinline__ u16 f2bf(float f) {
  u32 u = __builtin_bit_cast(u32, f);
  return (u16)((u + 0x7fffu + ((u >> 16) & 1u)) >> 16);
}
__device__ __forceinline__ float bf2f(u16 h) {
  u32 u = ((u32)h) << 16;
  return __builtin_bit_cast(float, u);
}
__device__ __forceinline__ float sigf(float x) { return 1.0f / (1.0f + __expf(-x)); }
__device__ __forceinline__ float tanha(float x) { return 1.0f - 2.0f / (__expf(2.0f * x) + 1.0f); }

// 2-level grid barrier (R1-proven form), monotone gens. Requires grid == 256.
__device__ __forceinline__ void gbar(int* bar, int gen) {
  __syncthreads();
  if (threadIdx.x == 0) {
    __threadfence();
    int grp = (int)blockIdx.x >> 4;
    int old = __hip_atomic_fetch_add(bar + grp * 32, 1, __ATOMIC_RELAXED, __HIP_MEMORY_SCOPE_AGENT);
    if ((old & 15) == 15) {
      int rold = __hip_atomic_fetch_add(bar + 512, 1, __ATOMIC_RELAXED, __HIP_MEMORY_SCOPE_AGENT);
      if ((rold & 15) == 15)
        __hip_atomic_store(bar + 544, gen + 1, __ATOMIC_RELEASE, __HIP_MEMORY_SCOPE_AGENT);
    }
    for (int k = 0; k < SPIN_CAP; ++k) {
      if (__hip_atomic_load(bar + 544, __ATOMIC_RELAXED, __HIP_MEMORY_SCOPE_AGENT) >= gen + 1) break;
      __builtin_amdgcn_s_sleep(1);
    }
    __threadfence();
  }
  __syncthreads();
}

// 16-wg row-group barrier (same-r wgs share one XCD under gid%8 dispatch).
__device__ __forceinline__ void rbar(int* bar, int r, int gen) {
  __syncthreads();
  if (threadIdx.x == 0) {
    __threadfence();
    int old = __hip_atomic_fetch_add(bar + r * 32, 1, __ATOMIC_RELAXED, __HIP_MEMORY_SCOPE_AGENT);
    if ((old & 15) == 15)
      __hip_atomic_store(bar + 512 + r * 32, gen + 1, __ATOMIC_RELEASE, __HIP_MEMORY_SCOPE_AGENT);
    for (int k = 0; k < SPIN_CAP; ++k) {
      if (__hip_atomic_load(bar + 512 + r * 32, __ATOMIC_RELAXED, __HIP_MEMORY_SCOPE_AGENT) >= gen + 1) break;
      __builtin_amdgcn_s_sleep(1);
    }
    __threadfence();
  }
  __syncthreads();
}

__global__ void init_k(float* __restrict__ out, const float* __restrict__ bout,
                       char* __restrict__ ws) {
  int* bar = (int*)(ws + BAR_OFF);
  int i = blockIdx.x * 256 + threadIdx.x;
  float bo = bout[0];
  for (int j = i; j < NT * NB; j += 256 * 256) out[j] = bo;
  if (i < NBAR_INTS) bar[i] = 0;
  if (i == 0) out[NT * NB] = 0.0f;
}

__global__ __launch_bounds__(1024, 4) void lstm_main(
    const float* __restrict__ xg, const float* __restrict__ Win, const float* __restrict__ bin,
    const float* __restrict__ Wih0, const float* __restrict__ bih0,
    const float* __restrict__ Whh0, const float* __restrict__ bhh0,
    const float* __restrict__ Wih1, const float* __restrict__ bih1,
    const float* __restrict__ Whh1, const float* __restrict__ bhh1,
    const float* __restrict__ Wout, float* __restrict__ out, char* __restrict__ ws) {
  __shared__ __align__(16) char lraw[65536];
  u16* gFu = (u16*)lraw;               // [4][32][40] bf16 (aliased over staging)
  float* sv = (float*)(lraw + 32768);  // [16][2] f32 var partials (aliased)
  u16* wb = (u16*)(ws + WB_OFF);
  float* b0 = (float*)(ws + B0_OFF);
  float* b1 = (float*)(ws + B1_OFF);
  u16* x0b = (u16*)(ws + X0_OFF);
  u16* htb = (u16*)(ws + HT_OFF);
  u16* ht0b = (u16*)(ws + HT0_OFF);
  u16* g0b = (u16*)(ws + G0_OFF);
  u16* g1b = (u16*)(ws + G1_OFF);
  float* vspb = (float*)(ws + VSP_OFF);
  float* normp = (float*)(ws + NRM_OFF);
  int* bar = (int*)(ws + BAR_OFF);
  int* gb = bar + 1024;

  const int tid = threadIdx.x;
  const int gid = blockIdx.x;
  const int gtid = gid * 1024 + tid;
  // r = gid&15: same-r wgs (who exchange row-wise activations) satisfy gid%8 == r%8
  // -> one XCD under round-robin dispatch -> ht/ht0/x0/g0b reads are XCD-local.
  const int r = gid & 15, c = gid >> 4;
  const int rbase = r * 32, cbase = c * 32;
  const int w = tid >> 6, lane = tid & 63, l15 = lane & 15, kg = lane >> 4;
  const int g = w >> 2, m = (w >> 1) & 1, n = w & 1;  // wave's fragment: gate g, m/n halves
  const int urow = tid >> 5, ucol = tid & 31;          // update-phase element
  const int ub = rbase + urow, uh = cbase + ucol;

  // loop-invariant per-thread preloads
  float winr[16];
  #pragma unroll
  for (int j = 0; j < 16; ++j) winr[j] = Win[(size_t)uh * NX4 + j];
  const float binr = bin[uh];
  const float woutr = Wout[uh];

  // ================= prologue =================
  {
    const float* srcs[4] = {Wih0, Whh0, Wih1, Whh1};
    #pragma unroll
    for (int mm = 0; mm < 4; ++mm) {
      const float4* s4 = (const float4*)srcs[mm];
      ushort4* d4 = (ushort4*)(wb + (size_t)mm * 2048 * 512);
      float4 v = s4[gtid];
      ushort4 o;
      o.x = f2bf(v.x); o.y = f2bf(v.y); o.z = f2bf(v.z); o.w = f2bf(v.w);
      d4[gtid] = o;
    }
    if (gtid < 2048) { b0[gtid] = bih0[gtid] + bhh0[gtid]; b1[gtid] = bih1[gtid] + bhh1[gtid]; }
    if (gtid < 512 * 512 / 2) ((u32*)htb)[gtid] = 0u;
    {
      const float* xr = xg + (size_t)ub * NX4;
      float a = binr;
      #pragma unroll
      for (int j = 0; j < 16; ++j) a += winr[j] * xr[j];
      x0b[(size_t)ub * 512 + uh] = f2bf(fmaxf(a, 0.0f));
    }
  }
  int ggen = 0, rgen = 0;
  gbar(gb, ggen); ++ggen;

  const float bias0l = b0[g * 512 + cbase + n * 16 + l15];
  const float bias1l = b1[g * 512 + cbase + n * 16 + l15];
  const int arow = m * 16 + l15;
  const int abase = arow << 11;
  const int axor = (arow & 7) << 4;
  const u16* Wl0 = wb + (size_t)(g * 512 + cbase + n * 16 + l15) * 512;
  float ctreg = 0.0f;  // this thread's cell-state element — register-resident

  // ================= time loop =================
  for (int t = 0; t < NT; ++t) {
    u16* g1cur = g1b + (size_t)(t & 1) * 1048576;   // parity double-buffer (kills WAR)
    // ---- P1: layer-0 gates + cell update ----
    #pragma unroll
    for (int p = 0; p < 4; ++p) {   // stage [x0 | ht] rows rbase..+32 (64KB, swizzled)
      int ch = p * 1024 + tid;
      int row = ch >> 7, cc = ch & 127;
      const u16* sp = (cc < 64) ? x0b + (size_t)(rbase + row) * 512 + cc * 8
                                : htb + (size_t)(rbase + row) * 512 + (cc - 64) * 8;
      u32x4 v = *(const u32x4*)sp;
      *(u32x4*)&lraw[(row << 11) | ((cc << 4) ^ ((row & 7) << 4))] = v;
    }
    __syncthreads();
    {
      f32x4 acc = {0.f, 0.f, 0.f, 0.f};
      const u16* W0 = Wl0;                       // Wih0 row
      const u16* W1 = Wl0 + 2048ull * 512;       // Whh0 row
      #pragma unroll
      for (int ks = 0; ks < 16; ++ks) {
        int kk = ks * 32 + kg * 8;
        bf16x8 a = *(const bf16x8*)&lraw[abase | (((kk >> 3) << 4) ^ axor)];
        bf16x8 q = *(const bf16x8*)(W0 + kk);
        acc = __builtin_amdgcn_mfma_f32_16x16x32_bf16(a, q, acc, 0, 0, 0);
      }
      #pragma unroll
      for (int ks = 0; ks < 16; ++ks) {
        int kk = ks * 32 + kg * 8;
        bf16x8 a = *(const bf16x8*)&lraw[abase | (((64 + (kk >> 3)) << 4) ^ axor)];
        bf16x8 q = *(const bf16x8*)(W1 + kk);
        acc = __builtin_amdgcn_mfma_f32_16x16x32_bf16(a, q, acc, 0, 0, 0);
      }
      __syncthreads();  // staging dead; reuse LDS as gFu
      #pragma unroll
      for (int q = 0; q < 4; ++q) {
        float v = acc[q] + bias0l;
        float a = (g == 2) ? tanha(v) : sigf(v);
        gFu[g * 1280 + (m * 16 + kg * 4 + q) * 40 + n * 16 + l15] = f2bf(a);
      }
    }
    __syncthreads();
    {
      u16 gi = gFu[0 * 1280 + urow * 40 + ucol];
      u16 gf = gFu[1 * 1280 + urow * 40 + ucol];
      u16 gc = gFu[2 * 1280 + urow * 40 + ucol];
      u16 go = gFu[3 * 1280 + urow * 40 + ucol];
      float i0 = bf2f(gi), f0 = bf2f(gf), c0 = bf2f(gc), o0 = bf2f(go);
      ctreg = f0 * ctreg + i0 * c0;
      float h0v = o0 * tanha(ctreg);
      size_t eo = (size_t)ub * 512 + uh;
      ht0b[eo] = f2bf(h0v);
      g0b[0 * 262144 + eo] = gi;
      g0b[1 * 262144 + eo] = gf;
      g0b[2 * 262144 + eo] = gc;
      g0b[3 * 262144 + eo] = go;
    }
    rbar(bar, r, rgen); ++rgen;   // group-r only: P2 stages group-r rows

    // ---- P2: layer-1 raw gates (direct global write) ----
    #pragma unroll
    for (int p = 0; p < 4; ++p) {   // stage [x0 | ht0]
      int ch = p * 1024 + tid;
      int row = ch >> 7, cc = ch & 127;
      const u16* sp = (cc < 64) ? x0b + (size_t)(rbase + row) * 512 + cc * 8
                                : ht0b + (size_t)(rbase + row) * 512 + (cc - 64) * 8;
      u32x4 v = *(const u32x4*)sp;
      *(u32x4*)&lraw[(row << 11) | ((cc << 4) ^ ((row & 7) << 4))] = v;
    }
    __syncthreads();
    {
      f32x4 acc = {0.f, 0.f, 0.f, 0.f};
      const u16* W0 = Wl0 + 2ull * 2048 * 512;   // Wih1
      const u16* W1 = Wl0 + 3ull * 2048 * 512;   // Whh1
      #pragma unroll
      for (int ks = 0; ks < 16; ++ks) {
        int kk = ks * 32 + kg * 8;
        bf16x8 a = *(const bf16x8*)&lraw[abase | (((kk >> 3) << 4) ^ axor)];
        bf16x8 q = *(const bf16x8*)(W0 + kk);
        acc = __builtin_amdgcn_mfma_f32_16x16x32_bf16(a, q, acc, 0, 0, 0);
      }
      #pragma unroll
      for (int ks = 0; ks < 16; ++ks) {
        int kk = ks * 32 + kg * 8;
        bf16x8 a = *(const bf16x8*)&lraw[abase | (((64 + (kk >> 3)) << 4) ^ axor)];
        bf16x8 q = *(const bf16x8*)(W1 + kk);
        acc = __builtin_amdgcn_mfma_f32_16x16x32_bf16(a, q, acc, 0, 0, 0);
      }
      #pragma unroll
      for (int q = 0; q < 4; ++q) {
        int b_ = rbase + m * 16 + kg * 4 + q;
        g1cur[(size_t)g * 262144 + (size_t)b_ * 512 + cbase + n * 16 + l15] = f2bf(acc[q] + bias1l);
      }
    }
    gbar(gb, ggen); ++ggen;   // global: P3 reads group-c's g1 rows

    // ---- P3: [B,B] score matmuls + layer-1 update + outputs ----
    {
      f32x4 acc = {0.f, 0.f, 0.f, 0.f};
      const u16* As = g0b + (size_t)g * 262144 + (size_t)(rbase + m * 16 + l15) * 512;
      const u16* Bs = g1cur + (size_t)g * 262144 + (size_t)(cbase + n * 16 + l15) * 512;
      #pragma unroll
      for (int ks = 0; ks < 16; ++ks) {
        int kk = ks * 32 + kg * 8;
        bf16x8 a = *(const bf16x8*)(As + kk);
        bf16x8 q = *(const bf16x8*)(Bs + kk);
        acc = __builtin_amdgcn_mfma_f32_16x16x32_bf16(a, q, acc, 0, 0, 0);
      }
      float s1 = acc[0] + acc[1] + acc[2] + acc[3];
      float s2 = acc[0] * acc[0] + acc[1] * acc[1] + acc[2] * acc[2] + acc[3] * acc[3];
      #pragma unroll
      for (int off = 32; off > 0; off >>= 1) { s1 += __shfl_xor(s1, off); s2 += __shfl_xor(s2, off); }
      if (lane == 0) { sv[w * 2] = s1; sv[w * 2 + 1] = s2; }
      #pragma unroll
      for (int q = 0; q < 4; ++q)
        gFu[g * 1280 + (m * 16 + kg * 4 + q) * 40 + n * 16 + l15] = f2bf(acc[q]);
    }
    __syncthreads();
    {
      float i1 = sigf(bf2f(gFu[0 * 1280 + urow * 40 + ucol]));
      float f1 = sigf(bf2f(gFu[1 * 1280 + urow * 40 + ucol]));
      float c1 = tanha(bf2f(gFu[2 * 1280 + urow * 40 + ucol]));
      float o1 = sigf(bf2f(gFu[3 * 1280 + urow * 40 + ucol]));
      ctreg = f1 * ctreg + i1 * c1;
      float hv = o1 * tanha(ctreg);
      htb[(size_t)ub * 512 + uh] = f2bf(hv);
      float op = hv * woutr;
      op += __shfl_down(op, 16, 32);
      op += __shfl_down(op, 8, 32);
      op += __shfl_down(op, 4, 32);
      op += __shfl_down(op, 2, 32);
      op += __shfl_down(op, 1, 32);
      if ((tid & 31) == 0) atomicAdd(out + (size_t)t * NB + ub, op);
      if (tid < 8) {   // per-wg variance slot: NO global contention
        int gg = tid >> 1, part = tid & 1;
        float val = sv[(gg * 4 + 0) * 2 + part] + sv[(gg * 4 + 1) * 2 + part] +
                    sv[(gg * 4 + 2) * 2 + part] + sv[(gg * 4 + 3) * 2 + part];
        vspb[((size_t)gid * 8 + tid) * 368 + t] = val;
      }
      if (t + 1 < NT) {
        const float* xr = xg + ((size_t)(t + 1) * NB + ub) * NX4;
        float a = binr;
        #pragma unroll
        for (int j = 0; j < 16; ++j) a += winr[j] * xr[j];
        x0b[(size_t)ub * 512 + uh] = f2bf(fmaxf(a, 0.0f));
      }
    }
    rbar(bar, r, rgen); ++rgen;   // group-r only: P1(t+1) stages group-r rows
  }

  // ================= epilogue: distributed variance + norm =================
  gbar(gb, ggen); ++ggen;
  float* red = (float*)lraw;
  const float invN = 1.0f / 262144.0f;
  for (int tt = gid; tt < NT; tt += 256) {
    int slot = tid >> 7;   // 0..7 = (gate, part)
    int j = tid & 127;
    float v = vspb[((size_t)j * 8 + slot) * 368 + tt] +
              vspb[((size_t)(j + 128) * 8 + slot) * 368 + tt];
    #pragma unroll
    for (int off = 32; off > 0; off >>= 1) v += __shfl_xor(v, off);
    __syncthreads();
    if (lane == 0) red[w] = v;   // wave w covers slot w>>1
    __syncthreads();
    if (tid == 0) {
      float var4 = 0.0f;
      #pragma unroll
      for (int gg2 = 0; gg2 < 4; ++gg2) {
        float sum = red[gg2 * 4 + 0] + red[gg2 * 4 + 1];
        float sq  = red[gg2 * 4 + 2] + red[gg2 * 4 + 3];
        float mean = sum * invN;
        var4 += sq * invN - mean * mean;
      }
      normp[tt] = var4 * 0.25f;
    }
    __syncthreads();
  }
  gbar(gb, ggen); ++ggen;
  if (gid == 0) {
    float s = (tid < NT) ? normp[tid] : 0.0f;
    #pragma unroll
    for (int off = 32; off > 0; off >>= 1) s += __shfl_xor(s, off);
    __syncthreads();
    if (lane == 0) red[w] = s;
    __syncthreads();
    if (tid == 0) {
      float tot = 0.0f;
      #pragma unroll
      for (int jj = 0; jj < 16; ++jj) tot += red[jj];
      out[NT * NB] = tot / (float)NT;
    }
  }
}

extern "C" void kernel_launch(void* const* d_in, const int* in_sizes, int n_in,
                              void* d_out, int out_size, void* d_ws, size_t ws_size,
                              hipStream_t stream) {
  const float* xg = (const float*)d_in[0];
  const float* Win = (const float*)d_in[1];
  const float* bin = (const float*)d_in[2];
  const float* Wih0 = (const float*)d_in[3];
  const float* bih0 = (const float*)d_in[4];
  const float* Whh0 = (const float*)d_in[5];
  const float* bhh0 = (const float*)d_in[6];
  const float* Wih1 = (const float*)d_in[7];
  const float* bih1 = (const float*)d_in[8];
  const float* Whh1 = (const float*)d_in[9];
  const float* bhh1 = (const float*)d_in[10];
  const float* Wout = (const float*)d_in[11];
  const float* bout = (const float*)d_in[12];
  float* out = (float*)d_out;
  char* ws = (char*)d_ws;

  hipLaunchKernelGGL(init_k, dim3(256), dim3(256), 0, stream, out, bout, ws);

  void* args[] = {(void*)&xg, (void*)&Win, (void*)&bin, (void*)&Wih0, (void*)&bih0,
                  (void*)&Whh0, (void*)&bhh0, (void*)&Wih1, (void*)&bih1,
                  (void*)&Whh1, (void*)&bhh1, (void*)&Wout, (void*)&out, (void*)&ws};
  hipLaunchCooperativeKernel((void*)lstm_main, dim3(256), dim3(1024), args, 0, stream);
}

// Round 9
// 21200.427 us; speedup vs baseline: 14.0602x; 1.6677x over previous
//
#include <hip/hip_runtime.h>

// ---- problem constants ----
#define NT 365
#define NB 512          // ngrid == hidden
#define NX4 16

typedef __attribute__((ext_vector_type(8))) short bf16x8;
typedef __attribute__((ext_vector_type(4))) float f32x4;
typedef __attribute__((ext_vector_type(4))) unsigned int u32x4;
typedef unsigned short u16;
typedef unsigned int u32;

// ---- workspace layout (bytes) ----
static constexpr size_t WB_OFF  = 0;                                   // 4 x [2048][512] bf16
static constexpr size_t B0_OFF  = WB_OFF + 4ull * 2048 * 512 * 2;      // 2048 f32
static constexpr size_t B1_OFF  = B0_OFF + 2048 * 4;
static constexpr size_t X0_OFF  = B1_OFF + 2048 * 4;                   // [512][512] bf16
static constexpr size_t HT_OFF  = X0_OFF + 512 * 512 * 2;
static constexpr size_t HT0_OFF = HT_OFF + 512 * 512 * 2;
static constexpr size_t G0_OFF  = HT0_OFF + 512 * 512 * 2;             // 4 x [512][512] bf16
static constexpr size_t G1_OFF  = G0_OFF + 4ull * 512 * 512 * 2;       // 4 x [512][512] bf16
static constexpr size_t CT_OFF  = G1_OFF + 4ull * 512 * 512 * 2;       // [512][512] f32
static constexpr size_t VSP_OFF = CT_OFF + 512ull * 512 * 4;           // [256 wg][8 slot][368] f32
static constexpr size_t NRM_OFF = VSP_OFF + 256ull * 8 * 368 * 4;      // [368] f32

__device__ __forceinline__ u16 f2bf(float f) {
  u32 u = __builtin_bit_cast(u32, f);
  return (u16)((u + 0x7fffu + ((u >> 16) & 1u)) >> 16);
}
__device__ __forceinline__ float bf2f(u16 h) {
  u32 u = ((u32)h) << 16;
  return __builtin_bit_cast(float, u);
}
__device__ __forceinline__ float sigf(float x) { return 1.0f / (1.0f + __expf(-x)); }
__device__ __forceinline__ float tanha(float x) { return 1.0f - 2.0f / (__expf(2.0f * x) + 1.0f); }

// ================= prep: weight conversion, bias fold, state init, x0(t=0), out bias =================
__global__ __launch_bounds__(1024) void prep_k(
    const float* __restrict__ xg, const float* __restrict__ Win, const float* __restrict__ bin,
    const float* __restrict__ Wih0, const float* __restrict__ bih0,
    const float* __restrict__ Whh0, const float* __restrict__ bhh0,
    const float* __restrict__ Wih1, const float* __restrict__ bih1,
    const float* __restrict__ Whh1, const float* __restrict__ bhh1,
    const float* __restrict__ bout, float* __restrict__ out, char* __restrict__ ws) {
  u16* wb = (u16*)(ws + WB_OFF);
  float* b0 = (float*)(ws + B0_OFF);
  float* b1 = (float*)(ws + B1_OFF);
  u16* x0b = (u16*)(ws + X0_OFF);
  u16* htb = (u16*)(ws + HT_OFF);
  float* ctb = (float*)(ws + CT_OFF);
  const int gtid = blockIdx.x * 1024 + threadIdx.x;   // 0..262143

  const float* srcs[4] = {Wih0, Whh0, Wih1, Whh1};
  #pragma unroll
  for (int mm = 0; mm < 4; ++mm) {
    const float4* s4 = (const float4*)srcs[mm];
    float4 v = s4[gtid];
    ushort4 o;
    o.x = f2bf(v.x); o.y = f2bf(v.y); o.z = f2bf(v.z); o.w = f2bf(v.w);
    ((ushort4*)(wb + (size_t)mm * 2048 * 512))[gtid] = o;
  }
  if (gtid < 2048) { b0[gtid] = bih0[gtid] + bhh0[gtid]; b1[gtid] = bih1[gtid] + bhh1[gtid]; }
  if (gtid < 131072) ((u32*)htb)[gtid] = 0u;
  ctb[gtid] = 0.0f;
  { // x0 for t=0: one element per thread
    int b = gtid >> 9, h = gtid & 511;
    const float* xr = xg + (size_t)b * NX4;
    const float* wr = Win + (size_t)h * NX4;
    float a = bin[h];
    #pragma unroll
    for (int j = 0; j < 16; ++j) a += wr[j] * xr[j];
    x0b[gtid] = f2bf(fmaxf(a, 0.0f));
  }
  { // out = bias
    float bo = bout[0];
    for (int j = gtid; j < NT * NB; j += 262144) out[j] = bo;
  }
}

// ================= P1: layer-0 gates + cell update =================
__global__ __launch_bounds__(1024) void p1_k(char* __restrict__ ws) {
  __shared__ __align__(16) char lraw[65536];
  u16* gFu = (u16*)lraw;
  u16* wb = (u16*)(ws + WB_OFF);
  float* b0 = (float*)(ws + B0_OFF);
  u16* x0b = (u16*)(ws + X0_OFF);
  u16* htb = (u16*)(ws + HT_OFF);
  u16* ht0b = (u16*)(ws + HT0_OFF);
  u16* g0b = (u16*)(ws + G0_OFF);
  float* ctb = (float*)(ws + CT_OFF);

  const int tid = threadIdx.x, gid = blockIdx.x;
  const int r = gid >> 4, c = gid & 15;   // c%8 = XCD -> same-c wgs share L2-resident weight slice
  const int rbase = r * 32, cbase = c * 32;
  const int w = tid >> 6, lane = tid & 63, l15 = lane & 15, kg = lane >> 4;
  const int g = w >> 2, m = (w >> 1) & 1, n = w & 1;
  const int urow = tid >> 5, ucol = tid & 31;
  const int ub = rbase + urow, uh = cbase + ucol;
  const int arow = m * 16 + l15, abase = arow << 11, axor = (arow & 7) << 4;
  const u16* Wl0 = wb + (size_t)(g * 512 + cbase + n * 16 + l15) * 512;
  const float bias0l = b0[g * 512 + cbase + n * 16 + l15];

  #pragma unroll
  for (int p = 0; p < 4; ++p) {   // stage [x0 | ht] rows rbase..+32 (64KB, swizzled)
    int ch = p * 1024 + tid;
    int row = ch >> 7, cc = ch & 127;
    const u16* sp = (cc < 64) ? x0b + (size_t)(rbase + row) * 512 + cc * 8
                              : htb + (size_t)(rbase + row) * 512 + (cc - 64) * 8;
    u32x4 v = *(const u32x4*)sp;
    *(u32x4*)&lraw[(row << 11) | ((cc << 4) ^ ((row & 7) << 4))] = v;
  }
  __syncthreads();
  f32x4 acc = {0.f, 0.f, 0.f, 0.f};
  {
    const u16* W0 = Wl0;                       // Wih0 row
    const u16* W1 = Wl0 + 2048ull * 512;       // Whh0 row
    #pragma unroll
    for (int ks = 0; ks < 16; ++ks) {
      int kk = ks * 32 + kg * 8;
      bf16x8 a = *(const bf16x8*)&lraw[abase | (((kk >> 3) << 4) ^ axor)];
      bf16x8 q = *(const bf16x8*)(W0 + kk);
      acc = __builtin_amdgcn_mfma_f32_16x16x32_bf16(a, q, acc, 0, 0, 0);
    }
    #pragma unroll
    for (int ks = 0; ks < 16; ++ks) {
      int kk = ks * 32 + kg * 8;
      bf16x8 a = *(const bf16x8*)&lraw[abase | (((64 + (kk >> 3)) << 4) ^ axor)];
      bf16x8 q = *(const bf16x8*)(W1 + kk);
      acc = __builtin_amdgcn_mfma_f32_16x16x32_bf16(a, q, acc, 0, 0, 0);
    }
  }
  __syncthreads();  // staging dead; reuse LDS as gFu
  #pragma unroll
  for (int q = 0; q < 4; ++q) {
    float v = acc[q] + bias0l;
    float a = (g == 2) ? tanha(v) : sigf(v);
    gFu[g * 1280 + (m * 16 + kg * 4 + q) * 40 + n * 16 + l15] = f2bf(a);
  }
  __syncthreads();
  {
    u16 gi = gFu[0 * 1280 + urow * 40 + ucol];
    u16 gf = gFu[1 * 1280 + urow * 40 + ucol];
    u16 gc = gFu[2 * 1280 + urow * 40 + ucol];
    u16 go = gFu[3 * 1280 + urow * 40 + ucol];
    float i0 = bf2f(gi), f0 = bf2f(gf), c0 = bf2f(gc), o0 = bf2f(go);
    size_t eo = (size_t)ub * 512 + uh;
    float ctv = ctb[eo];
    ctv = f0 * ctv + i0 * c0;
    float h0v = o0 * tanha(ctv);
    ctb[eo] = ctv;
    ht0b[eo] = f2bf(h0v);
    g0b[0 * 262144 + eo] = gi;
    g0b[1 * 262144 + eo] = gf;
    g0b[2 * 262144 + eo] = gc;
    g0b[3 * 262144 + eo] = go;
  }
}

// ================= P2: layer-1 raw gates =================
__global__ __launch_bounds__(1024) void p2_k(char* __restrict__ ws) {
  __shared__ __align__(16) char lraw[65536];
  u16* wb = (u16*)(ws + WB_OFF);
  float* b1 = (float*)(ws + B1_OFF);
  u16* x0b = (u16*)(ws + X0_OFF);
  u16* ht0b = (u16*)(ws + HT0_OFF);
  u16* g1b = (u16*)(ws + G1_OFF);

  const int tid = threadIdx.x, gid = blockIdx.x;
  const int r = gid >> 4, c = gid & 15;
  const int rbase = r * 32, cbase = c * 32;
  const int w = tid >> 6, lane = tid & 63, l15 = lane & 15, kg = lane >> 4;
  const int g = w >> 2, m = (w >> 1) & 1, n = w & 1;
  const int arow = m * 16 + l15, abase = arow << 11, axor = (arow & 7) << 4;
  const u16* Wl0 = wb + (size_t)(g * 512 + cbase + n * 16 + l15) * 512;
  const float bias1l = b1[g * 512 + cbase + n * 16 + l15];

  #pragma unroll
  for (int p = 0; p < 4; ++p) {   // stage [x0 | ht0]
    int ch = p * 1024 + tid;
    int row = ch >> 7, cc = ch & 127;
    const u16* sp = (cc < 64) ? x0b + (size_t)(rbase + row) * 512 + cc * 8
                              : ht0b + (size_t)(rbase + row) * 512 + (cc - 64) * 8;
    u32x4 v = *(const u32x4*)sp;
    *(u32x4*)&lraw[(row << 11) | ((cc << 4) ^ ((row & 7) << 4))] = v;
  }
  __syncthreads();
  f32x4 acc = {0.f, 0.f, 0.f, 0.f};
  {
    const u16* W0 = Wl0 + 2ull * 2048 * 512;   // Wih1
    const u16* W1 = Wl0 + 3ull * 2048 * 512;   // Whh1
    #pragma unroll
    for (int ks = 0; ks < 16; ++ks) {
      int kk = ks * 32 + kg * 8;
      bf16x8 a = *(const bf16x8*)&lraw[abase | (((kk >> 3) << 4) ^ axor)];
      bf16x8 q = *(const bf16x8*)(W0 + kk);
      acc = __builtin_amdgcn_mfma_f32_16x16x32_bf16(a, q, acc, 0, 0, 0);
    }
    #pragma unroll
    for (int ks = 0; ks < 16; ++ks) {
      int kk = ks * 32 + kg * 8;
      bf16x8 a = *(const bf16x8*)&lraw[abase | (((64 + (kk >> 3)) << 4) ^ axor)];
      bf16x8 q = *(const bf16x8*)(W1 + kk);
      acc = __builtin_amdgcn_mfma_f32_16x16x32_bf16(a, q, acc, 0, 0, 0);
    }
  }
  #pragma unroll
  for (int q = 0; q < 4; ++q) {
    int b_ = rbase + m * 16 + kg * 4 + q;
    g1b[(size_t)g * 262144 + (size_t)b_ * 512 + cbase + n * 16 + l15] = f2bf(acc[q] + bias1l);
  }
}

// ================= P3: [B,B] score matmuls + layer-1 update + outputs =================
__global__ __launch_bounds__(1024) void p3_k(
    char* __restrict__ ws, const float* __restrict__ xg, const float* __restrict__ Win,
    const float* __restrict__ bin, const float* __restrict__ Wout,
    float* __restrict__ out, int t) {
  __shared__ u16 gFu[5120];
  __shared__ float sv[32];
  u16* x0b = (u16*)(ws + X0_OFF);
  u16* htb = (u16*)(ws + HT_OFF);
  u16* g0b = (u16*)(ws + G0_OFF);
  u16* g1b = (u16*)(ws + G1_OFF);
  float* ctb = (float*)(ws + CT_OFF);
  float* vspb = (float*)(ws + VSP_OFF);

  const int tid = threadIdx.x, gid = blockIdx.x;
  const int r = gid >> 4, c = gid & 15;
  const int rbase = r * 32, cbase = c * 32;
  const int w = tid >> 6, lane = tid & 63, l15 = lane & 15, kg = lane >> 4;
  const int g = w >> 2, m = (w >> 1) & 1, n = w & 1;
  const int urow = tid >> 5, ucol = tid & 31;
  const int ub = rbase + urow, uh = cbase + ucol;

  {
    f32x4 acc = {0.f, 0.f, 0.f, 0.f};
    const u16* As = g0b + (size_t)g * 262144 + (size_t)(rbase + m * 16 + l15) * 512;
    const u16* Bs = g1b + (size_t)g * 262144 + (size_t)(cbase + n * 16 + l15) * 512;
    #pragma unroll
    for (int ks = 0; ks < 16; ++ks) {
      int kk = ks * 32 + kg * 8;
      bf16x8 a = *(const bf16x8*)(As + kk);
      bf16x8 q = *(const bf16x8*)(Bs + kk);
      acc = __builtin_amdgcn_mfma_f32_16x16x32_bf16(a, q, acc, 0, 0, 0);
    }
    float s1 = acc[0] + acc[1] + acc[2] + acc[3];
    float s2 = acc[0] * acc[0] + acc[1] * acc[1] + acc[2] * acc[2] + acc[3] * acc[3];
    #pragma unroll
    for (int off = 32; off > 0; off >>= 1) { s1 += __shfl_xor(s1, off); s2 += __shfl_xor(s2, off); }
    if (lane == 0) { sv[w * 2] = s1; sv[w * 2 + 1] = s2; }
    #pragma unroll
    for (int q = 0; q < 4; ++q)
      gFu[g * 1280 + (m * 16 + kg * 4 + q) * 40 + n * 16 + l15] = f2bf(acc[q]);
  }
  __syncthreads();
  {
    float i1 = sigf(bf2f(gFu[0 * 1280 + urow * 40 + ucol]));
    float f1 = sigf(bf2f(gFu[1 * 1280 + urow * 40 + ucol]));
    float c1 = tanha(bf2f(gFu[2 * 1280 + urow * 40 + ucol]));
    float o1 = sigf(bf2f(gFu[3 * 1280 + urow * 40 + ucol]));
    size_t eo = (size_t)ub * 512 + uh;
    float ctv = ctb[eo];
    ctv = f1 * ctv + i1 * c1;
    float hv = o1 * tanha(ctv);
    ctb[eo] = ctv;
    htb[eo] = f2bf(hv);
    float op = hv * Wout[uh];
    op += __shfl_down(op, 16, 32);
    op += __shfl_down(op, 8, 32);
    op += __shfl_down(op, 4, 32);
    op += __shfl_down(op, 2, 32);
    op += __shfl_down(op, 1, 32);
    if ((tid & 31) == 0) atomicAdd(out + (size_t)t * NB + ub, op);
    if (tid < 8) {   // per-wg variance slot
      int gg = tid >> 1, part = tid & 1;
      float val = sv[(gg * 4 + 0) * 2 + part] + sv[(gg * 4 + 1) * 2 + part] +
                  sv[(gg * 4 + 2) * 2 + part] + sv[(gg * 4 + 3) * 2 + part];
      vspb[((size_t)gid * 8 + tid) * 368 + t] = val;
    }
    if (t + 1 < NT) {   // next step's input projection for this element
      const float* xr = xg + ((size_t)(t + 1) * NB + ub) * NX4;
      const float* wr = Win + (size_t)uh * NX4;
      float a = bin[uh];
      #pragma unroll
      for (int j = 0; j < 16; ++j) a += wr[j] * xr[j];
      x0b[eo] = f2bf(fmaxf(a, 0.0f));
    }
  }
}

// ================= variance per timestep =================
__global__ __launch_bounds__(256) void var_k(char* __restrict__ ws) {
  __shared__ float sred[8];
  float* vspb = (float*)(ws + VSP_OFF);
  float* normp = (float*)(ws + NRM_OFF);
  const int tt = blockIdx.x;
  const int tid = threadIdx.x;
  const int s = tid >> 5, jb = tid & 31;
  float v = 0.0f;
  for (int j = jb; j < 256; j += 32) v += vspb[((size_t)j * 8 + s) * 368 + tt];
  #pragma unroll
  for (int off = 16; off > 0; off >>= 1) v += __shfl_xor(v, off, 32);
  if (jb == 0) sred[s] = v;
  __syncthreads();
  if (tid == 0) {
    const float invN = 1.0f / 262144.0f;
    float var4 = 0.0f;
    #pragma unroll
    for (int gg = 0; gg < 4; ++gg) {
      float sum = sred[gg * 2 + 0];
      float sq  = sred[gg * 2 + 1];
      float mean = sum * invN;
      var4 += sq * invN - mean * mean;
    }
    normp[tt] = var4 * 0.25f;
  }
}

__global__ __launch_bounds__(512) void final_k(char* __restrict__ ws, float* __restrict__ out) {
  __shared__ float red[8];
  float* normp = (float*)(ws + NRM_OFF);
  const int tid = threadIdx.x;
  float s = (tid < NT) ? normp[tid] : 0.0f;
  #pragma unroll
  for (int off = 32; off > 0; off >>= 1) s += __shfl_xor(s, off);
  if ((tid & 63) == 0) red[tid >> 6] = s;
  __syncthreads();
  if (tid == 0) {
    float tot = 0.0f;
    #pragma unroll
    for (int j = 0; j < 8; ++j) tot += red[j];
    out[NT * NB] = tot / (float)NT;
  }
}

extern "C" void kernel_launch(void* const* d_in, const int* in_sizes, int n_in,
                              void* d_out, int out_size, void* d_ws, size_t ws_size,
                              hipStream_t stream) {
  const float* xg = (const float*)d_in[0];
  const float* Win = (const float*)d_in[1];
  const float* bin = (const float*)d_in[2];
  const float* Wih0 = (const float*)d_in[3];
  const float* bih0 = (const float*)d_in[4];
  const float* Whh0 = (const float*)d_in[5];
  const float* bhh0 = (const float*)d_in[6];
  const float* Wih1 = (const float*)d_in[7];
  const float* bih1 = (const float*)d_in[8];
  const float* Whh1 = (const float*)d_in[9];
  const float* bhh1 = (const float*)d_in[10];
  const float* Wout = (const float*)d_in[11];
  const float* bout = (const float*)d_in[12];
  float* out = (float*)d_out;
  char* ws = (char*)d_ws;

  hipLaunchKernelGGL(prep_k, dim3(256), dim3(1024), 0, stream,
                     xg, Win, bin, Wih0, bih0, Whh0, bhh0, Wih1, bih1, Whh1, bhh1,
                     bout, out, ws);
  for (int t = 0; t < NT; ++t) {
    hipLaunchKernelGGL(p1_k, dim3(256), dim3(1024), 0, stream, ws);
    hipLaunchKernelGGL(p2_k, dim3(256), dim3(1024), 0, stream, ws);
    hipLaunchKernelGGL(p3_k, dim3(256), dim3(1024), 0, stream, ws, xg, Win, bin, Wout, out, t);
  }
  hipLaunchKernelGGL(var_k, dim3(365), dim3(256), 0, stream, ws);
  hipLaunchKernelGGL(final_k, dim3(1), dim3(512), 0, stream, ws, out);
}